// Round 3
// baseline (42776.089 us; speedup 1.0000x reference)
//
#include <hip/hip_runtime.h>
#include <math.h>

#define H 2048
#define S 8192
#define NBLK 256            // 256 blocks x 256 threads = 1024 waves
#define PWORD 1024          // 8B words per parity buffer (2 h-values each)
#define NREP 2              // hvt replicas
// hvt layout (u64): [rep][parity][PWORD]  = 2*2*1024*8B = 32 KB ws

typedef unsigned int u32x2 __attribute__((ext_vector_type(2)));
typedef unsigned int u32x4 __attribute__((ext_vector_type(4)));

// ---------------------------------------------------------------------------
// GEMM: U[t][j] = sum_k X[t][k] * Wxh[j][k]  (unchanged; ~1 ms, not the bottleneck)
// ---------------------------------------------------------------------------
__global__ __launch_bounds__(256) void gemm_xw(const float* __restrict__ X,
                                               const float* __restrict__ W,
                                               float* __restrict__ U) {
    __shared__ float As[16][64];
    __shared__ float Bs[16][64];
    const int tid = threadIdx.x;
    const int t0 = blockIdx.x * 64;
    const int j0 = blockIdx.y * 64;
    const int tx = tid & 15, ty = tid >> 4;

    float acc[4][4] = {};
    const int lr = tid >> 2;
    const int lk = (tid & 3) * 4;

    for (int k0 = 0; k0 < H; k0 += 16) {
        float4 a = *(const float4*)&X[(size_t)(t0 + lr) * H + k0 + lk];
        float4 b = *(const float4*)&W[(size_t)(j0 + lr) * H + k0 + lk];
        As[lk + 0][lr] = a.x; As[lk + 1][lr] = a.y; As[lk + 2][lr] = a.z; As[lk + 3][lr] = a.w;
        Bs[lk + 0][lr] = b.x; Bs[lk + 1][lr] = b.y; Bs[lk + 2][lr] = b.z; Bs[lk + 3][lr] = b.w;
        __syncthreads();
#pragma unroll
        for (int kk = 0; kk < 16; ++kk) {
            float4 av = *(const float4*)&As[kk][ty * 4];
            float4 bv = *(const float4*)&Bs[kk][tx * 4];
            float aa[4] = {av.x, av.y, av.z, av.w};
            float bb[4] = {bv.x, bv.y, bv.z, bv.w};
#pragma unroll
            for (int i = 0; i < 4; ++i)
#pragma unroll
                for (int j = 0; j < 4; ++j)
                    acc[i][j] += aa[i] * bb[j];
        }
        __syncthreads();
    }
#pragma unroll
    for (int i = 0; i < 4; ++i) {
        float4 v = {acc[i][0], acc[i][1], acc[i][2], acc[i][3]};
        *(float4*)&U[(size_t)(t0 + ty * 4 + i) * H + j0 + tx * 4] = v;
    }
}

// ---------------------------------------------------------------------------
// Init: parity-0 buffers = 0.0f values with epoch LSB 0 (h0 = 0, matches t=0).
// Parity-1 buffers = epoch LSB 1 per 4B (mismatches t=1's expected epoch 0).
// ---------------------------------------------------------------------------
__global__ void init_ws(unsigned long long* __restrict__ w) {
    int i = blockIdx.x * blockDim.x + threadIdx.x;
    if (i < NREP * 2 * PWORD)
        w[i] = ((i >> 10) & 1) ? 0x0000000100000001ull : 0ull;
}

// ---------------------------------------------------------------------------
// sc1 (L2-bypass, device-coherent) helpers.
// poll8: issue 8 x 16B loads covering the whole 8KB parity buffer for this
// lane's chunks, ONE vmcnt wait for all — a poll round costs ~1 RTT.
// ---------------------------------------------------------------------------
__device__ inline void poll8(const void* p0, const void* p1, u32x4 v[8]) {
    asm volatile(
        "global_load_dwordx4 %0, %8, off sc1\n\t"
        "global_load_dwordx4 %1, %8, off offset:1024 sc1\n\t"
        "global_load_dwordx4 %2, %8, off offset:2048 sc1\n\t"
        "global_load_dwordx4 %3, %8, off offset:3072 sc1\n\t"
        "global_load_dwordx4 %4, %9, off sc1\n\t"
        "global_load_dwordx4 %5, %9, off offset:1024 sc1\n\t"
        "global_load_dwordx4 %6, %9, off offset:2048 sc1\n\t"
        "global_load_dwordx4 %7, %9, off offset:3072 sc1\n\t"
        "s_waitcnt vmcnt(0)"
        : "=&v"(v[0]), "=&v"(v[1]), "=&v"(v[2]), "=&v"(v[3]),
          "=&v"(v[4]), "=&v"(v[5]), "=&v"(v[6]), "=&v"(v[7])
        : "v"(p0), "v"(p1)
        : "memory");
}
__device__ inline void st8_sc1(void* p, u32x2 v) {
    asm volatile("global_store_dwordx2 %0, %1, off sc1" :: "v"(p), "v"(v) : "memory");
}

// ---------------------------------------------------------------------------
// Wave-autonomous persistent recurrence. Each of the 1024 waves owns 2 rows:
//  - W_hh fragment (2 rows x its 32 h-columns) in 64 VGPRs.
//  - Polls ALL of h_{t-1}: 8 x dwordx4 sc1 loads/lane/round (one vmcnt),
//    FMAs 4-value chunks into 2 row-partials on arrival (per-4B epoch LSB
//    (t>>1)&1 validates; chunk consumed only when all 4 LSBs match).
//  - Fold-butterfly (6 shfls): lane parity p ends with row (2*gwid+p) total.
//  - tanh on all lanes, lane 0 stores out row-pair + publishes the wave's
//    8B packed word to both replicas. NO LDS, NO __syncthreads, no
//    cross-wave coupling anywhere in the step loop -> publish latency is
//    this wave's own detect + ~300 cyc, not a max over 4 sibling waves.
//  - Skew<=1-step dataflow argument unchanged (now at wave granularity):
//    publishing t+2 requires consuming all t+1, which requires every wave
//    published t+1, which requires every wave consumed t. Epoch parity
//    disambiguates the 2-step slot reuse; any tearing is caught per-4B.
//  - Sticky fallback to __hip_atomic_load polling after 1024 idle rounds
//    (sc1 insurance; proven-dead in R2 but kept).
// ---------------------------------------------------------------------------
__global__ __launch_bounds__(256) void rnn_recur(float* __restrict__ out,
                                                 const float* __restrict__ Whh,
                                                 const float* __restrict__ bias,
                                                 unsigned long long* __restrict__ hvt) {
    const int tid  = threadIdx.x;
    const int lane = tid & 63;
    const int gwid = blockIdx.x * 4 + (tid >> 6);   // 0..1023
    const int row0 = gwid * 2;
    const int myrow = row0 + (lane & 1);

    // W fragment: w0/w1[i] = Whh[row0(+1)][4*(i*64+lane) .. +3]  (coalesced)
    float4 w0[8], w1[8];
#pragma unroll
    for (int i = 0; i < 8; ++i) {
        w0[i] = *(const float4*)&Whh[(size_t)row0 * H + 4 * (i * 64 + lane)];
        w1[i] = *(const float4*)&Whh[(size_t)(row0 + 1) * H + 4 * (i * 64 + lane)];
    }
    const float bb = bias[myrow];

    char* const hb_rep = (char*)hvt + (size_t)(blockIdx.x & 1) * (2 * PWORD * 8);
    int fb = 0;

    for (int t = 0; t < S; ++t) {
        float u_val = out[(size_t)t * H + myrow];   // prefetch, hides under poll
        const unsigned int ep = ((unsigned int)t >> 1) & 1u;
        char* hb = hb_rep + (size_t)(t & 1) * (PWORD * 8);
        const char* p0 = hb + lane * 16;
        const char* p1 = p0 + 4096;

        float a0 = 0.f, a1 = 0.f;
        unsigned int pend = 0xFFu;
        int spin = 0;
        while (pend && !fb) {
            u32x4 v[8];
            poll8(p0, p1, v);
#pragma unroll
            for (int i = 0; i < 8; ++i) {
                if (pend & (1u << i)) {
                    const u32x4 c = v[i];
                    if ((((c.x ^ ep) | (c.y ^ ep) | (c.z ^ ep) | (c.w ^ ep)) & 1u) == 0u) {
                        const float h0 = __uint_as_float(c.x), h1 = __uint_as_float(c.y);
                        const float h2 = __uint_as_float(c.z), h3 = __uint_as_float(c.w);
                        a0 += w0[i].x * h0 + w0[i].y * h1 + w0[i].z * h2 + w0[i].w * h3;
                        a1 += w1[i].x * h0 + w1[i].y * h1 + w1[i].z * h2 + w1[i].w * h3;
                        pend &= ~(1u << i);
                    }
                }
            }
            if (pend) {
                __builtin_amdgcn_s_sleep(1);
                if (++spin > 1024) fb = 1;
            }
        }
        while (pend) {   // insurance path: known-good 8B agent atomics
            const unsigned long long* q = (const unsigned long long*)hb;
#pragma unroll
            for (int i = 0; i < 8; ++i)
                if (pend & (1u << i)) {
                    const int c2 = 2 * (i * 64 + lane);
                    unsigned long long lo = __hip_atomic_load(q + c2, __ATOMIC_RELAXED,
                                                              __HIP_MEMORY_SCOPE_AGENT);
                    unsigned long long hi = __hip_atomic_load(q + c2 + 1, __ATOMIC_RELAXED,
                                                              __HIP_MEMORY_SCOPE_AGENT);
                    u32x4 c;
                    c.x = (unsigned int)lo; c.y = (unsigned int)(lo >> 32);
                    c.z = (unsigned int)hi; c.w = (unsigned int)(hi >> 32);
                    if ((((c.x ^ ep) | (c.y ^ ep) | (c.z ^ ep) | (c.w ^ ep)) & 1u) == 0u) {
                        const float h0 = __uint_as_float(c.x), h1 = __uint_as_float(c.y);
                        const float h2 = __uint_as_float(c.z), h3 = __uint_as_float(c.w);
                        a0 += w0[i].x * h0 + w0[i].y * h1 + w0[i].z * h2 + w0[i].w * h3;
                        a1 += w1[i].x * h0 + w1[i].y * h1 + w1[i].z * h2 + w1[i].w * h3;
                        pend &= ~(1u << i);
                    }
                }
            if (pend) __builtin_amdgcn_s_sleep(1);
        }

        // Fold rows across lane bit 0, then 5-stage butterfly: lane parity p
        // ends holding the full dot for row (row0+p).
        {
            float s = (lane & 1) ? a0 : a1;
            float r = __shfl_xor(s, 1, 64);
            a0 = ((lane & 1) ? a1 : a0) + r;
        }
#pragma unroll
        for (int m = 2; m <= 32; m <<= 1)
            a0 += __shfl_xor(a0, m, 64);

        const float val = tanhf(a0 + u_val + bb);
        const float vodd = __shfl(val, 1, 64);
        if (lane == 0) {
            float2 o2 = {val, vodd};
            *(float2*)&out[(size_t)t * H + row0] = o2;                  // h_t over U
            if (t == S - 1) *(float2*)&out[(size_t)S * H + row0] = o2;  // h_T
            const unsigned int e2 = (((unsigned int)(t + 1)) >> 1) & 1u;
            u32x2 pk;
            pk.x = (__float_as_uint(val)  & ~1u) | e2;
            pk.y = (__float_as_uint(vodd) & ~1u) | e2;
            unsigned long long* dst = hvt + (size_t)((t + 1) & 1) * PWORD + gwid;
            st8_sc1(dst, pk);                 // replica 0
            st8_sc1(dst + 2 * PWORD, pk);     // replica 1
        }
    }
}

extern "C" void kernel_launch(void* const* d_in, const int* in_sizes, int n_in,
                              void* d_out, int out_size, void* d_ws, size_t ws_size,
                              hipStream_t stream) {
    const float* X    = (const float*)d_in[0];  // (8192, 2048)
    const float* Wxh  = (const float*)d_in[1];  // (2048, 2048)
    const float* Whh  = (const float*)d_in[2];  // (2048, 2048)
    const float* bias = (const float*)d_in[3];  // (2048,)
    float* out = (float*)d_out;
    unsigned long long* hvt = (unsigned long long*)d_ws;   // 32 KB

    // Phase 0: init replicated packed h buffers.
    init_ws<<<(NREP * 2 * PWORD + 255) / 256, 256, 0, stream>>>(hvt);

    // Phase 1: U = X @ Wxh^T into out[0 .. S*H)
    dim3 ggrid(S / 64, H / 64);
    gemm_xw<<<ggrid, 256, 0, stream>>>(X, Wxh, out);

    // Phase 2: wave-autonomous sequential recurrence (cooperative launch).
    void* args[] = {(void*)&out, (void*)&Whh, (void*)&bias, (void*)&hvt};
    hipLaunchCooperativeKernel((void*)rnn_recur, dim3(NBLK), dim3(256), args, 0, stream);
}

// Round 4
// 28801.596 us; speedup vs baseline: 1.4852x; 1.4852x over previous
//
#include <hip/hip_runtime.h>
#include <math.h>

#define H 2048
#define S 8192
#define RPB 8              // hidden rows per block
#define NBLK (H / RPB)     // 256 blocks = 256 CUs
#define PARBYTES (H * 4)   // 8 KB per parity buffer (2048 packed fp32)
#define NREP 2             // hvt replicas
// ws layout (bytes): [rep][parity][PARBYTES] = 2*2*8KB = 32 KB

typedef unsigned int u32x4 __attribute__((ext_vector_type(4)));

// ---------------------------------------------------------------------------
// GEMM: U[t][j] = sum_k X[t][k] * Wxh[j][k]  (unchanged; ~1 ms, not the bottleneck)
// ---------------------------------------------------------------------------
__global__ __launch_bounds__(256) void gemm_xw(const float* __restrict__ X,
                                               const float* __restrict__ W,
                                               float* __restrict__ U) {
    __shared__ float As[16][64];
    __shared__ float Bs[16][64];
    const int tid = threadIdx.x;
    const int t0 = blockIdx.x * 64;
    const int j0 = blockIdx.y * 64;
    const int tx = tid & 15, ty = tid >> 4;

    float acc[4][4] = {};
    const int lr = tid >> 2;
    const int lk = (tid & 3) * 4;

    for (int k0 = 0; k0 < H; k0 += 16) {
        float4 a = *(const float4*)&X[(size_t)(t0 + lr) * H + k0 + lk];
        float4 b = *(const float4*)&W[(size_t)(j0 + lr) * H + k0 + lk];
        As[lk + 0][lr] = a.x; As[lk + 1][lr] = a.y; As[lk + 2][lr] = a.z; As[lk + 3][lr] = a.w;
        Bs[lk + 0][lr] = b.x; Bs[lk + 1][lr] = b.y; Bs[lk + 2][lr] = b.z; Bs[lk + 3][lr] = b.w;
        __syncthreads();
#pragma unroll
        for (int kk = 0; kk < 16; ++kk) {
            float4 av = *(const float4*)&As[kk][ty * 4];
            float4 bv = *(const float4*)&Bs[kk][tx * 4];
            float aa[4] = {av.x, av.y, av.z, av.w};
            float bb[4] = {bv.x, bv.y, bv.z, bv.w};
#pragma unroll
            for (int i = 0; i < 4; ++i)
#pragma unroll
                for (int j = 0; j < 4; ++j)
                    acc[i][j] += aa[i] * bb[j];
        }
        __syncthreads();
    }
#pragma unroll
    for (int i = 0; i < 4; ++i) {
        float4 v = {acc[i][0], acc[i][1], acc[i][2], acc[i][3]};
        *(float4*)&U[(size_t)(t0 + ty * 4 + i) * H + j0 + tx * 4] = v;
    }
}

// ---------------------------------------------------------------------------
// Init: parity-0 buffers = 0.0f with epoch LSB 0 (h0 = 0, matches t=0).
// Parity-1 buffers = LSB 1 per 4B (mismatches epoch 0 expected at t=1, and
// cannot false-match any look-ahead epoch either).
// ---------------------------------------------------------------------------
__global__ void init_ws(unsigned long long* __restrict__ w) {
    int i = blockIdx.x * blockDim.x + threadIdx.x;
    if (i < NREP * 2 * (PARBYTES / 8))
        w[i] = ((i >> 10) & 1) ? 0x0000000100000001ull : 0ull;
}

// ---------------------------------------------------------------------------
// sc1 (L2-bypass, device-coherent) helpers.
// poll4: both parities in one vmcnt bundle — 2 cur chunks + 2 next chunks.
// Thread's chunks are ADJACENT (byte tid*32 .. +31), so one base per parity
// with offset:16 covers both.
// ---------------------------------------------------------------------------
__device__ inline void poll4(const void* pc, const void* pn,
                             u32x4& c0, u32x4& c1, u32x4& n0, u32x4& n1) {
    asm volatile(
        "global_load_dwordx4 %0, %4, off sc1\n\t"
        "global_load_dwordx4 %1, %4, off offset:16 sc1\n\t"
        "global_load_dwordx4 %2, %5, off sc1\n\t"
        "global_load_dwordx4 %3, %5, off offset:16 sc1\n\t"
        "s_waitcnt vmcnt(0)"
        : "=&v"(c0), "=&v"(c1), "=&v"(n0), "=&v"(n1)
        : "v"(pc), "v"(pn)
        : "memory");
}
__device__ inline void st16_sc1(void* p, u32x4 v) {
    asm volatile("global_store_dwordx4 %0, %1, off sc1" :: "v"(p), "v"(v) : "memory");
}

// ---------------------------------------------------------------------------
// Persistent recurrence, R2 block-cooperative structure + two new levers:
//  (a) dual-parity poll-ahead: while waiting for step t's straggler chunks,
//      FMA early-arriving step t+1 chunks (other parity) into accN; pend/acc
//      carry across steps, so a step often STARTS mostly-consumed. Absorbs
//      publish jitter instead of re-paying max-straggler each step.
//  (b) flag-based combine (no __syncthreads): each wave posts its 8 row
//      partials + monotone step flag to LDS and immediately resumes polling;
//      wave 0 lanes 0-7 spin on the 4 flags (LDS RTT ~50cy), combine, tanh,
//      publish. Safety: part[] is parity-double-buffered and step t+2's
//      overwrite of part[t&1] is gated (via the global dataflow) by our own
//      t+1 publish, which follows the step-t combine in program order.
//  Epoch-LSB scheme per 4B as in R2; look-ahead epochs always distinguish
//  stale (t-1) from fresh (t+1) contents (LSBs of (t-1)>>1 and (t+1)>>1
//  differ). Liveness escape: after 4096 idle rounds, re-read cur chunks via
//  known-good 8B agent atomics (normally dead; sc1 proven in R2/R3).
// ---------------------------------------------------------------------------
__global__ __launch_bounds__(256) void rnn_recur(float* __restrict__ out,
                                                 const float* __restrict__ Whh,
                                                 const float* __restrict__ bias,
                                                 unsigned long long* __restrict__ hvt) {
    __shared__ float part[2][4][RPB];   // [parity][wave][row]
    __shared__ int   flag[2][4];        // [parity][wave], monotone step marks
    const int tid  = threadIdx.x;
    const int lane = tid & 63;
    const int wid  = tid >> 6;
    const int r0   = blockIdx.x * RPB;

    if (tid < 8) flag[tid >> 2][tid & 3] = 0;
    __syncthreads();

    // W fragment: wv[j][i] = Whh[r0+j][8*tid + 4*i .. +3]
    // (thread's polled h columns are 8*tid .. 8*tid+7)
    float4 wv[RPB][2];
#pragma unroll
    for (int j = 0; j < RPB; ++j)
#pragma unroll
        for (int i = 0; i < 2; ++i)
            wv[j][i] = *(const float4*)&Whh[(size_t)(r0 + j) * H + 8 * tid + 4 * i];

    const float bb = bias[r0 + (tid & 7)];
    char* const hrep = (char*)hvt + (size_t)(blockIdx.x & 1) * (2 * PARBYTES);

    float acc[RPB] = {}, accN[RPB] = {};
    unsigned int pend = 3u, pendN = 3u;

    for (int t = 0; t < S; ++t) {
        // Prefetch this step's U value (wave0 rows; hides under poll).
        float u_val = out[(size_t)t * H + r0 + (tid & 7)];

        const unsigned int ep  = ((unsigned int)t >> 1) & 1u;
        const unsigned int epN = ((unsigned int)(t + 1) >> 1) & 1u;
        const char* pc = hrep + (size_t)(t & 1) * PARBYTES + tid * 32;
        const char* pn = hrep + (size_t)((t + 1) & 1) * PARBYTES + tid * 32;

        int spin = 0;
        while (pend) {
            u32x4 c[2], n[2];
            poll4(pc, pn, c[0], c[1], n[0], n[1]);
            if (__builtin_expect(spin > 4096, 0)) {
                // Liveness escape: known-good 8B agent atomics for cur chunks.
                const unsigned long long* q = (const unsigned long long*)pc;
#pragma unroll
                for (int i = 0; i < 2; ++i) {
                    unsigned long long lo = __hip_atomic_load(q + 2 * i, __ATOMIC_RELAXED,
                                                              __HIP_MEMORY_SCOPE_AGENT);
                    unsigned long long hi = __hip_atomic_load(q + 2 * i + 1, __ATOMIC_RELAXED,
                                                              __HIP_MEMORY_SCOPE_AGENT);
                    c[i].x = (unsigned int)lo; c[i].y = (unsigned int)(lo >> 32);
                    c[i].z = (unsigned int)hi; c[i].w = (unsigned int)(hi >> 32);
                }
            }
#pragma unroll
            for (int i = 0; i < 2; ++i) {
                if (pend & (1u << i)) {
                    const u32x4 v = c[i];
                    if ((((v.x ^ ep) | (v.y ^ ep) | (v.z ^ ep) | (v.w ^ ep)) & 1u) == 0u) {
                        const float h0 = __uint_as_float(v.x), h1 = __uint_as_float(v.y);
                        const float h2 = __uint_as_float(v.z), h3 = __uint_as_float(v.w);
#pragma unroll
                        for (int j = 0; j < RPB; ++j)
                            acc[j] += wv[j][i].x * h0 + wv[j][i].y * h1 +
                                      wv[j][i].z * h2 + wv[j][i].w * h3;
                        pend &= ~(1u << i);
                    }
                }
                if (pendN & (1u << i)) {
                    const u32x4 v = n[i];
                    if ((((v.x ^ epN) | (v.y ^ epN) | (v.z ^ epN) | (v.w ^ epN)) & 1u) == 0u) {
                        const float h0 = __uint_as_float(v.x), h1 = __uint_as_float(v.y);
                        const float h2 = __uint_as_float(v.z), h3 = __uint_as_float(v.w);
#pragma unroll
                        for (int j = 0; j < RPB; ++j)
                            accN[j] += wv[j][i].x * h0 + wv[j][i].y * h1 +
                                       wv[j][i].z * h2 + wv[j][i].w * h3;
                        pendN &= ~(1u << i);
                    }
                }
            }
            if (pend) {
                __builtin_amdgcn_s_sleep(1);
                ++spin;
            }
        }

        // Folding butterfly: 8 rows x 64 lanes -> 1 row/lane (10 shfls).
#pragma unroll
        for (int j = 0; j < 4; ++j) {
            float s = (lane & 1) ? acc[j] : acc[j + 4];
            float r = __shfl_xor(s, 1, 64);
            acc[j] = ((lane & 1) ? acc[j + 4] : acc[j]) + r;
        }
#pragma unroll
        for (int j = 0; j < 2; ++j) {
            float s = (lane & 2) ? acc[j] : acc[j + 2];
            float r = __shfl_xor(s, 2, 64);
            acc[j] = ((lane & 2) ? acc[j + 2] : acc[j]) + r;
        }
        {
            float s = (lane & 4) ? acc[0] : acc[1];
            float r = __shfl_xor(s, 4, 64);
            acc[0] = ((lane & 4) ? acc[1] : acc[0]) + r;
        }
#pragma unroll
        for (int m = 8; m <= 32; m <<= 1)
            acc[0] += __shfl_xor(acc[0], m, 64);

        // Post wave partials + flag; resume polling immediately (no barrier).
        if (lane < 8)
            part[t & 1][wid][((lane & 1) << 2) | (lane & 2) | ((lane & 4) >> 2)] = acc[0];
        __threadfence_block();
        if (lane == 0)
            __hip_atomic_store(&flag[t & 1][wid], t + 1, __ATOMIC_RELEASE,
                               __HIP_MEMORY_SCOPE_WORKGROUP);

        if (wid == 0 && lane < 8) {
            while (__hip_atomic_load(&flag[t & 1][0], __ATOMIC_ACQUIRE,
                                     __HIP_MEMORY_SCOPE_WORKGROUP) < t + 1 ||
                   __hip_atomic_load(&flag[t & 1][1], __ATOMIC_ACQUIRE,
                                     __HIP_MEMORY_SCOPE_WORKGROUP) < t + 1 ||
                   __hip_atomic_load(&flag[t & 1][2], __ATOMIC_ACQUIRE,
                                     __HIP_MEMORY_SCOPE_WORKGROUP) < t + 1 ||
                   __hip_atomic_load(&flag[t & 1][3], __ATOMIC_ACQUIRE,
                                     __HIP_MEMORY_SCOPE_WORKGROUP) < t + 1) { }
            const float sum = part[t & 1][0][lane] + part[t & 1][1][lane] +
                              part[t & 1][2][lane] + part[t & 1][3][lane];
            const float val = tanhf(sum + u_val + bb);
            out[(size_t)t * H + r0 + lane] = val;                  // h_t over U
            if (t == S - 1) out[(size_t)S * H + r0 + lane] = val;  // h_T
            // Gather 4 adjacent rows into one 16B word; lanes 0 and 4 store.
            const float s0 = __shfl(val, (lane & 4) | 0, 64);
            const float s1 = __shfl(val, (lane & 4) | 1, 64);
            const float s2 = __shfl(val, (lane & 4) | 2, 64);
            const float s3 = __shfl(val, (lane & 4) | 3, 64);
            if ((lane & 3) == 0) {
                const unsigned int e2 = (((unsigned int)(t + 1)) >> 1) & 1u;
                u32x4 pk;
                pk.x = (__float_as_uint(s0) & ~1u) | e2;
                pk.y = (__float_as_uint(s1) & ~1u) | e2;
                pk.z = (__float_as_uint(s2) & ~1u) | e2;
                pk.w = (__float_as_uint(s3) & ~1u) | e2;
                char* dst = (char*)hvt + (size_t)((t + 1) & 1) * PARBYTES +
                            (size_t)r0 * 4 + (lane & 4) * 4;
#pragma unroll
                for (int rep = 0; rep < NREP; ++rep)
                    st16_sc1(dst + (size_t)rep * (2 * PARBYTES), pk);
            }
        }

        // Rotate: next-step state becomes current.
#pragma unroll
        for (int j = 0; j < RPB; ++j) { acc[j] = accN[j]; accN[j] = 0.f; }
        pend = pendN; pendN = 3u;
    }
}

extern "C" void kernel_launch(void* const* d_in, const int* in_sizes, int n_in,
                              void* d_out, int out_size, void* d_ws, size_t ws_size,
                              hipStream_t stream) {
    const float* X    = (const float*)d_in[0];  // (8192, 2048)
    const float* Wxh  = (const float*)d_in[1];  // (2048, 2048)
    const float* Whh  = (const float*)d_in[2];  // (2048, 2048)
    const float* bias = (const float*)d_in[3];  // (2048,)
    float* out = (float*)d_out;
    unsigned long long* hvt = (unsigned long long*)d_ws;   // 32 KB

    // Phase 0: init replicated packed h buffers.
    init_ws<<<(NREP * 2 * (PARBYTES / 8) + 255) / 256, 256, 0, stream>>>(hvt);

    // Phase 1: U = X @ Wxh^T into out[0 .. S*H)
    dim3 ggrid(S / 64, H / 64);
    gemm_xw<<<ggrid, 256, 0, stream>>>(X, Wxh, out);

    // Phase 2: sequential recurrence (cooperative launch; data-flow sync).
    void* args[] = {(void*)&out, (void*)&Whh, (void*)&bias, (void*)&hvt};
    hipLaunchCooperativeKernel((void*)rnn_recur, dim3(NBLK), dim3(256), args, 0, stream);
}

// Round 6
// 19783.719 us; speedup vs baseline: 2.1622x; 1.4558x over previous
//
#include <hip/hip_runtime.h>
#include <math.h>

#define H 2048
#define S 8192
#define RPB 16             // hidden rows per block
#define NBLK (H / RPB)     // 128 blocks
#define PARBYTES (H * 4)   // 8 KB per parity buffer (2048 packed fp32)
#define NREP 2             // hvt replicas
// ws layout (bytes): [rep][parity][PARBYTES] = 2*2*8KB = 32 KB

typedef unsigned int u32x4 __attribute__((ext_vector_type(4)));

// ---------------------------------------------------------------------------
// GEMM: U[t][j] = sum_k X[t][k] * Wxh[j][k]  (unchanged; ~1 ms, not the bottleneck)
// ---------------------------------------------------------------------------
__global__ __launch_bounds__(256) void gemm_xw(const float* __restrict__ X,
                                               const float* __restrict__ W,
                                               float* __restrict__ U) {
    __shared__ float As[16][64];
    __shared__ float Bs[16][64];
    const int tid = threadIdx.x;
    const int t0 = blockIdx.x * 64;
    const int j0 = blockIdx.y * 64;
    const int tx = tid & 15, ty = tid >> 4;

    float acc[4][4] = {};
    const int lr = tid >> 2;
    const int lk = (tid & 3) * 4;

    for (int k0 = 0; k0 < H; k0 += 16) {
        float4 a = *(const float4*)&X[(size_t)(t0 + lr) * H + k0 + lk];
        float4 b = *(const float4*)&W[(size_t)(j0 + lr) * H + k0 + lk];
        As[lk + 0][lr] = a.x; As[lk + 1][lr] = a.y; As[lk + 2][lr] = a.z; As[lk + 3][lr] = a.w;
        Bs[lk + 0][lr] = b.x; Bs[lk + 1][lr] = b.y; Bs[lk + 2][lr] = b.z; Bs[lk + 3][lr] = b.w;
        __syncthreads();
#pragma unroll
        for (int kk = 0; kk < 16; ++kk) {
            float4 av = *(const float4*)&As[kk][ty * 4];
            float4 bv = *(const float4*)&Bs[kk][tx * 4];
            float aa[4] = {av.x, av.y, av.z, av.w};
            float bb[4] = {bv.x, bv.y, bv.z, bv.w};
#pragma unroll
            for (int i = 0; i < 4; ++i)
#pragma unroll
                for (int j = 0; j < 4; ++j)
                    acc[i][j] += aa[i] * bb[j];
        }
        __syncthreads();
    }
#pragma unroll
    for (int i = 0; i < 4; ++i) {
        float4 v = {acc[i][0], acc[i][1], acc[i][2], acc[i][3]};
        *(float4*)&U[(size_t)(t0 + ty * 4 + i) * H + j0 + tx * 4] = v;
    }
}

// ---------------------------------------------------------------------------
// Init. 2-bit epoch e=(t>>1)&3 is spread over a 16B chunk's four LSBs as
// [e&1, e>>1, e&1, e>>1]. Parity-0 init = all-zero (value 0 = h0, pattern
// e=0 -> matches t=0). Parity-1 init = LSB 1 per 4B (pattern e=3, mismatches
// t=1's expected e=0).
// ---------------------------------------------------------------------------
__global__ void init_ws(unsigned long long* __restrict__ w) {
    int i = blockIdx.x * blockDim.x + threadIdx.x;
    if (i < NREP * 2 * (PARBYTES / 8))
        w[i] = ((i >> 10) & 1) ? 0x0000000100000001ull : 0ull;
}

// ---------------------------------------------------------------------------
// sc1 (LLC-coherent) helpers. poll2: thread's two adjacent 16B chunks in one
// vmcnt bundle. Round body minimal: detection quantum ~= 1 LLC RTT.
// ---------------------------------------------------------------------------
__device__ inline void poll2(const void* pc, u32x4& c0, u32x4& c1) {
    asm volatile(
        "global_load_dwordx4 %0, %2, off sc1\n\t"
        "global_load_dwordx4 %1, %2, off offset:16 sc1\n\t"
        "s_waitcnt vmcnt(0)"
        : "=&v"(c0), "=&v"(c1)
        : "v"(pc)
        : "memory");
}
__device__ inline void st16_sc1(void* p, u32x4 v) {
    asm volatile("global_store_dwordx4 %0, %1, off sc1" :: "v"(p), "v"(v) : "memory");
}

// ---------------------------------------------------------------------------
// Persistent recurrence (128 blocks x 16 rows), R5 structure + race fix:
//  ROOT CAUSE of R5's post-timing divergence: successive publishes go to
//  the two parity buffers (8KB apart -> different channels) as RELAXED sc1
//  stores; visibility could reorder, letting a consumer finish step t-1 yet
//  still see the 4-step-stale value (same 1-bit epoch LSB) in the other
//  parity slot. Fix:
//   (1) s_waitcnt vmcnt(0) fence immediately BEFORE each publish (orders it
//       after the prior-step publish's arrival at the coherence point; ~free
//       since everything outstanding has retired by then). Publish now
//       precedes the out[] write so the fence never waits on an HBM store.
//   (2) 2-bit epoch spread over the chunk LSBs -> alias distance 8 steps.
//  Tear-safety unchanged (chunk validated as a unit, per-4B atomicity).
//  Skew<=1 dataflow argument otherwise unchanged.
// ---------------------------------------------------------------------------
__global__ __launch_bounds__(256) void rnn_recur(float* __restrict__ out,
                                                 const float* __restrict__ Whh,
                                                 const float* __restrict__ bias,
                                                 unsigned long long* __restrict__ hvt) {
    __shared__ float part[2][4][RPB];   // [parity][wave][row]
    const int tid  = threadIdx.x;
    const int lane = tid & 63;
    const int wid  = tid >> 6;
    const int r0   = blockIdx.x * RPB;

    // W fragment: wv[j][i] = Whh[r0+j][8*tid + 4*i .. +3]  (128 VGPRs)
    float4 wv[RPB][2];
#pragma unroll
    for (int j = 0; j < RPB; ++j)
#pragma unroll
        for (int i = 0; i < 2; ++i)
            wv[j][i] = *(const float4*)&Whh[(size_t)(r0 + j) * H + 8 * tid + 4 * i];

    const float bb = bias[r0 + (tid & 15)];
    char* const hrep = (char*)hvt + (size_t)(blockIdx.x & 1) * (2 * PARBYTES);

    for (int t = 0; t < S; ++t) {
        // Prefetch this step's U value (rows r0..r0+15; hides under poll).
        float u_val = out[(size_t)t * H + r0 + (tid & 15)];

        const unsigned int e  = ((unsigned int)t >> 1) & 3u;
        const unsigned int e0 = e & 1u, e1 = (e >> 1) & 1u;
        const char* pc = hrep + (size_t)(t & 1) * PARBYTES + tid * 32;

        float acc[RPB] = {};
        unsigned int pend = 3u;
        while (pend) {
            u32x4 c0, c1;
            poll2(pc, c0, c1);
#pragma unroll
            for (int i = 0; i < 2; ++i) {
                if (pend & (1u << i)) {
                    const u32x4 v = i ? c1 : c0;
                    if ((((v.x ^ e0) | (v.z ^ e0) | (v.y ^ e1) | (v.w ^ e1)) & 1u) == 0u) {
                        const float h0 = __uint_as_float(v.x), h1 = __uint_as_float(v.y);
                        const float h2 = __uint_as_float(v.z), h3 = __uint_as_float(v.w);
#pragma unroll
                        for (int j = 0; j < RPB; ++j)
                            acc[j] += wv[j][i].x * h0 + wv[j][i].y * h1 +
                                      wv[j][i].z * h2 + wv[j][i].w * h3;
                        pend &= ~(1u << i);
                    }
                }
            }
        }

        // Folding butterfly: 16 rows x 64 lanes -> 1 row/lane (depth 6).
#pragma unroll
        for (int j = 0; j < 8; ++j) {
            float s = (lane & 1) ? acc[j] : acc[j + 8];
            float r = __shfl_xor(s, 1, 64);
            acc[j] = ((lane & 1) ? acc[j + 8] : acc[j]) + r;
        }
#pragma unroll
        for (int j = 0; j < 4; ++j) {
            float s = (lane & 2) ? acc[j] : acc[j + 4];
            float r = __shfl_xor(s, 2, 64);
            acc[j] = ((lane & 2) ? acc[j + 4] : acc[j]) + r;
        }
#pragma unroll
        for (int j = 0; j < 2; ++j) {
            float s = (lane & 4) ? acc[j] : acc[j + 2];
            float r = __shfl_xor(s, 4, 64);
            acc[j] = ((lane & 4) ? acc[j + 2] : acc[j]) + r;
        }
        {
            float s = (lane & 8) ? acc[0] : acc[1];
            float r = __shfl_xor(s, 8, 64);
            acc[0] = ((lane & 8) ? acc[1] : acc[0]) + r;
        }
        acc[0] += __shfl_xor(acc[0], 16, 64);
        acc[0] += __shfl_xor(acc[0], 32, 64);

        // lane<16 holds row bitrev4(lane&15).
        if (lane < 16) {
            const int row = ((lane & 1) << 3) | ((lane & 2) << 1) |
                            ((lane & 4) >> 1) | ((lane & 8) >> 3);
            part[t & 1][wid][row] = acc[0];
        }
        __syncthreads();

        if (tid < RPB) {
            const float sum = part[t & 1][0][tid] + part[t & 1][1][tid] +
                              part[t & 1][2][tid] + part[t & 1][3][tid];
            const float val = tanhf(sum + u_val + bb);
            // Gather 4 adjacent rows into one 16B word; lanes 0,4,8,12 store.
            const float s0 = __shfl(val, (tid & 12) | 0, 64);
            const float s1 = __shfl(val, (tid & 12) | 1, 64);
            const float s2 = __shfl(val, (tid & 12) | 2, 64);
            const float s3 = __shfl(val, (tid & 12) | 3, 64);
            if ((tid & 3) == 0) {
                const unsigned int ee  = (((unsigned int)(t + 1)) >> 1) & 3u;
                const unsigned int ee0 = ee & 1u, ee1 = (ee >> 1) & 1u;
                u32x4 pk;
                pk.x = (__float_as_uint(s0) & ~1u) | ee0;
                pk.y = (__float_as_uint(s1) & ~1u) | ee1;
                pk.z = (__float_as_uint(s2) & ~1u) | ee0;
                pk.w = (__float_as_uint(s3) & ~1u) | ee1;
                char* dst = (char*)hvt + (size_t)((t + 1) & 1) * PARBYTES +
                            (size_t)(r0 + tid) * 4;
                // Store-store fence: prior-step publishes must be at the
                // coherence point before this step's publish issues. By now
                // all this wave's outstanding ops retired -> ~free.
                asm volatile("s_waitcnt vmcnt(0)" ::: "memory");
#pragma unroll
                for (int rep = 0; rep < NREP; ++rep)
                    st16_sc1(dst + (size_t)rep * (2 * PARBYTES), pk);
            }
            // out[] writes AFTER the publish so the fence never waits on them.
            out[(size_t)t * H + r0 + tid] = val;                  // h_t over U
            if (t == S - 1) out[(size_t)S * H + r0 + tid] = val;  // h_T
        }
        // No trailing barrier: next step's partials go to part[(t+1)&1]; reuse
        // of part[t&1] at t+2 is gated by the global dataflow (skew <= 1 step).
    }
}

extern "C" void kernel_launch(void* const* d_in, const int* in_sizes, int n_in,
                              void* d_out, int out_size, void* d_ws, size_t ws_size,
                              hipStream_t stream) {
    const float* X    = (const float*)d_in[0];  // (8192, 2048)
    const float* Wxh  = (const float*)d_in[1];  // (2048, 2048)
    const float* Whh  = (const float*)d_in[2];  // (2048, 2048)
    const float* bias = (const float*)d_in[3];  // (2048,)
    float* out = (float*)d_out;
    unsigned long long* hvt = (unsigned long long*)d_ws;   // 32 KB

    // Phase 0: init replicated packed h buffers.
    init_ws<<<(NREP * 2 * (PARBYTES / 8) + 255) / 256, 256, 0, stream>>>(hvt);

    // Phase 1: U = X @ Wxh^T into out[0 .. S*H)
    dim3 ggrid(S / 64, H / 64);
    gemm_xw<<<ggrid, 256, 0, stream>>>(X, Wxh, out);

    // Phase 2: sequential recurrence (cooperative launch; data-flow sync).
    void* args[] = {(void*)&out, (void*)&Whh, (void*)&bias, (void*)&hvt};
    hipLaunchCooperativeKernel((void*)rnn_recur, dim3(NBLK), dim3(256), args, 0, stream);
}